// Round 1
// baseline (731.888 us; speedup 1.0000x reference)
//
#include <hip/hip_runtime.h>

// GAT on line graph: E=131072 nodes, M=2097152 edges (+E self loops),
// IN=64, HEADS=4, CH=64, concat=False (head mean), then scatter-mean by rows
// (N=16384) and a final 64x64 linear.
//
// Pipeline:
//   k_project   : h = x @ W^T  [E,256]; a_src/a_dst = einsum(h, att)  [E,4]
//   k_fill      : bucket incoming edges per dst (cap 64), incl. self loops
//   k_aggregate : per-dst wave: in-register segment softmax (no segment-max,
//                 mathematically identical ratio) + weighted gather of h[src],
//                 head mean + bias, atomic scatter into agg[rows[e]]
//   k_final     : agg/deg @ w_weight^T + w_bias -> d_out

#define CAP 64

__device__ __forceinline__ float wave_reduce_sum(float v) {
#pragma unroll
  for (int off = 32; off > 0; off >>= 1) v += __shfl_xor(v, off, 64);
  return v;
}

// ---------------- Pass 1: projection + attention dot products ----------------
template <int ROWS>
__global__ __launch_bounds__(256, 2) void k_project(
    const float* __restrict__ x, const float* __restrict__ W,
    const float* __restrict__ att_src, const float* __restrict__ att_dst,
    float* __restrict__ h, float* __restrict__ a_src, float* __restrict__ a_dst) {
  __shared__ float wt[64 * 257];     // wt[c*257 + t] = W[t*64 + c]  (transposed, padded)
  __shared__ float xt[64 * ROWS];    // xt[c*ROWS + r] = x[(e0+r)*64 + c]
  const int t = threadIdx.x;
  const int e0 = blockIdx.x * ROWS;

#pragma unroll
  for (int i = 0; i < 64; ++i) {
    int idx = t + i * 256;                       // idx = tcol*64 + c
    wt[(idx & 63) * 257 + (idx >> 6)] = W[idx];
  }
#pragma unroll
  for (int i = 0; i < ROWS * 64 / 256; ++i) {
    int idx = t + i * 256;                       // idx = r*64 + c
    xt[(idx & 63) * ROWS + (idx >> 6)] = x[(size_t)e0 * 64 + idx];
  }
  __syncthreads();

  float acc[ROWS];
#pragma unroll
  for (int r = 0; r < ROWS; ++r) acc[r] = 0.f;

#pragma unroll 8
  for (int c = 0; c < 64; ++c) {
    float wv = wt[c * 257 + t];
    const float4* xr = (const float4*)&xt[c * ROWS];
#pragma unroll
    for (int j = 0; j < ROWS / 4; ++j) {
      float4 xv = xr[j];
      acc[j * 4 + 0] += xv.x * wv;
      acc[j * 4 + 1] += xv.y * wv;
      acc[j * 4 + 2] += xv.z * wv;
      acc[j * 4 + 3] += xv.w * wv;
    }
  }

  const int w = t >> 6, lane = t & 63;
  const float ats = att_src[w * 64 + lane];
  const float atd = att_dst[w * 64 + lane];
#pragma unroll
  for (int r = 0; r < ROWS; ++r) {
    h[(size_t)(e0 + r) * 256 + t] = acc[r];
    float s = wave_reduce_sum(acc[r] * ats);
    float d = wave_reduce_sum(acc[r] * atd);
    if (lane == 0) {
      a_src[(e0 + r) * 4 + w] = s;
      a_dst[(e0 + r) * 4 + w] = d;
    }
  }
}

// ---------------- Pass 2: bucket edges by dst ----------------
__global__ void k_fill(const int* __restrict__ ei, int M, int E,
                       int* __restrict__ cnt, int* __restrict__ csr) {
  int m = blockIdx.x * blockDim.x + threadIdx.x;
  int Mtot = M + E;
  if (m >= Mtot) return;
  int s, d;
  if (m < M) { s = ei[m]; d = ei[M + m]; }
  else       { s = m - M; d = s; }                 // self loop
  int pos = atomicAdd(&cnt[d], 1);
  if (pos < CAP) csr[(size_t)d * CAP + pos] = s;
}

// ---------------- Pass 3: softmax + gather aggregation ----------------
__global__ __launch_bounds__(256) void k_aggregate(
    const float* __restrict__ h, const float4* __restrict__ a_src,
    const float4* __restrict__ a_dst, const int* __restrict__ cnt,
    const int* __restrict__ csr, const int* __restrict__ rows,
    const float* __restrict__ bias, float* __restrict__ agg,
    int* __restrict__ degc, int E) {
  const int w = threadIdx.x >> 6, lane = threadIdx.x & 63;
  const int e = blockIdx.x * 4 + w;
  if (e >= E) return;

  int deg = cnt[e];
  if (deg > CAP) deg = CAP;
  float4 ad = a_dst[e];

  int src = 0;
  float ex0 = 0.f, ex1 = 0.f, ex2 = 0.f, ex3 = 0.f;
  if (lane < deg) {
    src = csr[(size_t)e * CAP + lane];
    float4 as = a_src[src];
    float l0 = as.x + ad.x; l0 = l0 > 0.f ? l0 : 0.2f * l0;
    float l1 = as.y + ad.y; l1 = l1 > 0.f ? l1 : 0.2f * l1;
    float l2 = as.z + ad.z; l2 = l2 > 0.f ? l2 : 0.2f * l2;
    float l3 = as.w + ad.w; l3 = l3 > 0.f ? l3 : 0.2f * l3;
    ex0 = expf(l0); ex1 = expf(l1); ex2 = expf(l2); ex3 = expf(l3);
  }
  float i0 = 1.f / (wave_reduce_sum(ex0) + 1e-16f);
  float i1 = 1.f / (wave_reduce_sum(ex1) + 1e-16f);
  float i2 = 1.f / (wave_reduce_sum(ex2) + 1e-16f);
  float i3 = 1.f / (wave_reduce_sum(ex3) + 1e-16f);

  float acc0 = 0.f, acc1 = 0.f, acc2 = 0.f, acc3 = 0.f;
  for (int k = 0; k < deg; ++k) {
    int sk = __shfl(src, k, 64);
    float a0 = __shfl(ex0, k, 64) * i0;
    float a1 = __shfl(ex1, k, 64) * i1;
    float a2 = __shfl(ex2, k, 64) * i2;
    float a3 = __shfl(ex3, k, 64) * i3;
    const float* hp = h + (size_t)sk * 256 + lane;
    acc0 += a0 * hp[0];
    acc1 += a1 * hp[64];
    acc2 += a2 * hp[128];
    acc3 += a3 * hp[192];
  }
  float outc = 0.25f * (acc0 + acc1 + acc2 + acc3) + bias[lane];
  int r = rows[e];
  atomicAdd(&agg[(size_t)r * 64 + lane], outc);
  if (lane == 0) atomicAdd(&degc[r], 1);
}

// ---------------- Pass 4: scatter-mean normalize + final linear ----------------
__global__ __launch_bounds__(256) void k_final(
    const float* __restrict__ agg, const int* __restrict__ degc,
    const float* __restrict__ wgt, const float* __restrict__ wb,
    float* __restrict__ out, int N) {
  __shared__ float wtt[64 * 65];     // wtt[k*65 + c] = wgt[c*64 + k]
  const int t = threadIdx.x;
#pragma unroll
  for (int i = 0; i < 16; ++i) {
    int idx = t + i * 256;                       // idx = c*64 + k
    wtt[(idx & 63) * 65 + (idx >> 6)] = wgt[idx];
  }
  __syncthreads();
  const int w = t >> 6, lane = t & 63;
  int n = blockIdx.x * 4 + w;
  if (n >= N) return;
  int dg = degc[n];
  float av = dg > 0 ? agg[(size_t)n * 64 + lane] / (float)dg : 0.f;
  float o = 0.f;
#pragma unroll
  for (int k = 0; k < 64; ++k) {
    o += __shfl(av, k, 64) * wtt[k * 65 + lane];
  }
  out[(size_t)n * 64 + lane] = o + wb[lane];
}

extern "C" void kernel_launch(void* const* d_in, const int* in_sizes, int n_in,
                              void* d_out, int out_size, void* d_ws, size_t ws_size,
                              hipStream_t stream) {
  const float* x       = (const float*)d_in[0];
  const int*   ei      = (const int*)d_in[1];
  const int*   rows    = (const int*)d_in[2];
  const float* W       = (const float*)d_in[3];
  const float* att_src = (const float*)d_in[4];
  const float* att_dst = (const float*)d_in[5];
  const float* bias    = (const float*)d_in[6];
  const float* wgt     = (const float*)d_in[7];
  const float* wb      = (const float*)d_in[8];

  const int E = in_sizes[0] / 64;     // 131072
  const int M = in_sizes[1] / 2;      // 2097152
  const int N = out_size / 64;        // 16384

  char* ws = (char*)d_ws;
  float* h     = (float*)ws;                                    // E*256 f32 = 128MB
  float* a_src = (float*)(ws + (size_t)E * 256 * 4);            // E*4 f32
  float* a_dst = a_src + (size_t)E * 4;                         // E*4 f32
  int*   cnt   = (int*)(a_dst + (size_t)E * 4);                 // E int
  int*   csr   = cnt + E;                                       // E*CAP int = 32MB
  float* agg   = (float*)(csr + (size_t)E * CAP);               // N*64 f32
  int*   degc  = (int*)(agg + (size_t)N * 64);                  // N int

  hipMemsetAsync(cnt, 0, (size_t)E * 4, stream);
  hipMemsetAsync(agg, 0, (size_t)N * 64 * 4 + (size_t)N * 4, stream);  // agg + degc

  k_project<16><<<E / 16, 256, 0, stream>>>(x, W, att_src, att_dst, h, a_src, a_dst);

  int Mtot = M + E;
  k_fill<<<(Mtot + 255) / 256, 256, 0, stream>>>(ei, M, E, cnt, csr);

  k_aggregate<<<(E + 3) / 4, 256, 0, stream>>>(
      h, (const float4*)a_src, (const float4*)a_dst, cnt, csr, rows, bias,
      agg, degc, E);

  k_final<<<(N + 3) / 4, 256, 0, stream>>>(agg, degc, wgt, wb, (float*)d_out, N);
}

// Round 2
// 497.457 us; speedup vs baseline: 1.4713x; 1.4713x over previous
//
#include <hip/hip_runtime.h>

// GAT on line graph. Pipeline:
//   k_prevs : cast W->bf16; vs[8][64] = W^T @ att_{src,dst}  (for exact fp32 logits)
//   k_cast  : x -> bf16; a_src/a_dst = x . vs  (fp32, exact)
//   k_proj  : MFMA bf16 GEMM h = x @ W^T, stored bf16 packed [E][ch][head] (64MB)
//   k_fill  : bucket incoming edges per dst (cap 64), incl. self loops
//   k_agg   : per-dst wave softmax (denominator-only, ratio-exact) + gather
//   k_final : scatter-mean normalize + 64x64 linear

#define CAP 64

using frag16 = __attribute__((ext_vector_type(8))) short;  // 8 bf16
using f32x4  = __attribute__((ext_vector_type(4))) float;

__device__ __forceinline__ float wave_reduce_sum(float v) {
#pragma unroll
  for (int off = 32; off > 0; off >>= 1) v += __shfl_xor(v, off, 64);
  return v;
}

__device__ __forceinline__ unsigned short f2bf(float f) {
  union { float f; unsigned u; } v; v.f = f;
  unsigned r = v.u + 0x7fffu + ((v.u >> 16) & 1u);
  return (unsigned short)(r >> 16);
}
__device__ __forceinline__ float bflo(unsigned u) {
  union { unsigned u; float f; } v; v.u = u << 16; return v.f;
}
__device__ __forceinline__ float bfhi(unsigned u) {
  union { unsigned u; float f; } v; v.u = u & 0xffff0000u; return v.f;
}

// ---------------- Pass 0: W cast + vs precompute ----------------
__global__ __launch_bounds__(256) void k_prevs(
    const float* __restrict__ W, const float* __restrict__ att_src,
    const float* __restrict__ att_dst, unsigned short* __restrict__ Wb,
    float* __restrict__ vs) {
  int t = blockIdx.x * 256 + threadIdx.x;    // 64 blocks -> 16384 = 256*64
  Wb[t] = f2bf(W[t]);
  if (blockIdx.x < 2) {
    int o = blockIdx.x * 256 + threadIdx.x;  // 0..511
    int j = o >> 6, c = o & 63;              // j: 0..3 src heads, 4..7 dst heads
    const float* att = (j < 4) ? att_src : att_dst;
    int hh = j & 3;
    float s = 0.f;
    for (int ch = 0; ch < 64; ++ch)
      s += W[(size_t)(hh * 64 + ch) * 64 + c] * att[hh * 64 + ch];
    vs[o] = s;
  }
}

// ---------------- Pass 1: x cast + exact attention dots ----------------
__global__ __launch_bounds__(256) void k_cast(
    const float* __restrict__ x, const float* __restrict__ vs,
    unsigned short* __restrict__ xb, float* __restrict__ a_src,
    float* __restrict__ a_dst, int E) {
  const int w = threadIdx.x >> 6, lane = threadIdx.x & 63;
  const int e = blockIdx.x * 4 + w;
  if (e >= E) return;
  float xv = x[(size_t)e * 64 + lane];
  xb[(size_t)e * 64 + lane] = f2bf(xv);
  float s0 = wave_reduce_sum(xv * vs[0 * 64 + lane]);
  float s1 = wave_reduce_sum(xv * vs[1 * 64 + lane]);
  float s2 = wave_reduce_sum(xv * vs[2 * 64 + lane]);
  float s3 = wave_reduce_sum(xv * vs[3 * 64 + lane]);
  float s4 = wave_reduce_sum(xv * vs[4 * 64 + lane]);
  float s5 = wave_reduce_sum(xv * vs[5 * 64 + lane]);
  float s6 = wave_reduce_sum(xv * vs[6 * 64 + lane]);
  float s7 = wave_reduce_sum(xv * vs[7 * 64 + lane]);
  if (lane == 0) {
    a_src[e * 4 + 0] = s0; a_src[e * 4 + 1] = s1;
    a_src[e * 4 + 2] = s2; a_src[e * 4 + 3] = s3;
    a_dst[e * 4 + 0] = s4; a_dst[e * 4 + 1] = s5;
    a_dst[e * 4 + 2] = s6; a_dst[e * 4 + 3] = s7;
  }
}

// ---------------- Pass 2: MFMA projection h = x @ W^T (bf16 out, packed) -----
// h2 layout: row e = 256 bf16, position ch*4 + head  (uint2 per ch holds 4 heads)
__global__ __launch_bounds__(256) void k_proj(
    const unsigned short* __restrict__ xb, const unsigned short* __restrict__ Wb,
    unsigned short* __restrict__ h2) {
  __shared__ unsigned short hstage[64 * 264];   // 64 rows, padded stride 264
  const int w = threadIdx.x >> 6, lane = threadIdx.x & 63;
  const int l15 = lane & 15, l4 = lane >> 4;
  const int e0 = blockIdx.x * 64 + w * 16;

  // A frags: row e0+l15, k-group l4 (8 consecutive k) -- same k-order as B.
  frag16 a0 = *(const frag16*)(xb + (size_t)(e0 + l15) * 64 + l4 * 8);
  frag16 a1 = *(const frag16*)(xb + (size_t)(e0 + l15) * 64 + 32 + l4 * 8);

  f32x4 acc[16];
#pragma unroll
  for (int nt = 0; nt < 16; ++nt) {
    // B frag: col t' = nt*16 + l15 (row of W), k-group l4
    const unsigned short* bp = Wb + (size_t)(nt * 16 + l15) * 64 + l4 * 8;
    frag16 b0 = *(const frag16*)(bp);
    frag16 b1 = *(const frag16*)(bp + 32);
    f32x4 c = {0.f, 0.f, 0.f, 0.f};
    c = __builtin_amdgcn_mfma_f32_16x16x32_bf16(a0, b0, c, 0, 0, 0);
    c = __builtin_amdgcn_mfma_f32_16x16x32_bf16(a1, b1, c, 0, 0, 0);
    acc[nt] = c;
  }

  // Repack: C elem (reg r): row_local = w*16 + l4*4 + r, col t' = nt*16+l15
  // t' = head*64 + ch  ->  ch = (nt&3)*16 + l15, head = nt>>2.
  // Pack 4 heads (nt0, nt0+4, nt0+8, nt0+12) -> ushort4 at hstage[row][ch*4]
#pragma unroll
  for (int nt0 = 0; nt0 < 4; ++nt0) {
    int ch = nt0 * 16 + l15;
#pragma unroll
    for (int r = 0; r < 4; ++r) {
      int row = w * 16 + l4 * 4 + r;
      ushort4 v;
      v.x = f2bf(acc[nt0][r]);
      v.y = f2bf(acc[nt0 + 4][r]);
      v.z = f2bf(acc[nt0 + 8][r]);
      v.w = f2bf(acc[nt0 + 12][r]);
      *(ushort4*)&hstage[row * 264 + ch * 4] = v;
    }
  }
  __syncthreads();

  // Coalesced writeout: thread t -> row t>>2, 128B chunk q = t&3
  const int row = threadIdx.x >> 2, q = threadIdx.x & 3;
  const float4* sp = (const float4*)(hstage + row * 264 + q * 64);
  float4* dp = (float4*)(h2 + ((size_t)blockIdx.x * 64 + row) * 256 + q * 64);
#pragma unroll
  for (int i = 0; i < 8; ++i) dp[i] = sp[i];
}

// ---------------- Pass 3: bucket edges by dst ----------------
__global__ void k_fill(const int* __restrict__ ei, int M, int E,
                       int* __restrict__ cnt, int* __restrict__ csr) {
  int m = blockIdx.x * blockDim.x + threadIdx.x;
  int Mtot = M + E;
  if (m >= Mtot) return;
  int s, d;
  if (m < M) { s = ei[m]; d = ei[M + m]; }
  else       { s = m - M; d = s; }                 // self loop
  int pos = atomicAdd(&cnt[d], 1);
  if (pos < CAP) csr[(size_t)d * CAP + pos] = s;
}

// ---------------- Pass 4: softmax + gather aggregation ----------------
__global__ __launch_bounds__(256) void k_agg(
    const uint2* __restrict__ h2, const float4* __restrict__ a_src,
    const float4* __restrict__ a_dst, const int* __restrict__ cnt,
    const int* __restrict__ csr, const int* __restrict__ rows,
    const float* __restrict__ bias, float* __restrict__ agg,
    int* __restrict__ degc, int E) {
  const int w = threadIdx.x >> 6, lane = threadIdx.x & 63;
  const int e = blockIdx.x * 4 + w;
  if (e >= E) return;

  int deg = cnt[e];
  if (deg > CAP) deg = CAP;
  float4 ad = a_dst[e];

  int src = 0;
  float ex0 = 0.f, ex1 = 0.f, ex2 = 0.f, ex3 = 0.f;
  if (lane < deg) {
    src = csr[(size_t)e * CAP + lane];
    float4 as = a_src[src];
    float l0 = as.x + ad.x; l0 = l0 > 0.f ? l0 : 0.2f * l0;
    float l1 = as.y + ad.y; l1 = l1 > 0.f ? l1 : 0.2f * l1;
    float l2 = as.z + ad.z; l2 = l2 > 0.f ? l2 : 0.2f * l2;
    float l3 = as.w + ad.w; l3 = l3 > 0.f ? l3 : 0.2f * l3;
    ex0 = expf(l0); ex1 = expf(l1); ex2 = expf(l2); ex3 = expf(l3);
  }
  float i0 = 1.f / (wave_reduce_sum(ex0) + 1e-16f);
  float i1 = 1.f / (wave_reduce_sum(ex1) + 1e-16f);
  float i2 = 1.f / (wave_reduce_sum(ex2) + 1e-16f);
  float i3 = 1.f / (wave_reduce_sum(ex3) + 1e-16f);

  float acc0 = 0.f, acc1 = 0.f, acc2 = 0.f, acc3 = 0.f;
  int k = 0;
  for (; k + 4 <= deg; k += 4) {
    int s0 = __shfl(src, k, 64),     s1 = __shfl(src, k + 1, 64);
    int s2 = __shfl(src, k + 2, 64), s3 = __shfl(src, k + 3, 64);
    uint2 v0 = h2[(size_t)s0 * 64 + lane];
    uint2 v1 = h2[(size_t)s1 * 64 + lane];
    uint2 v2 = h2[(size_t)s2 * 64 + lane];
    uint2 v3 = h2[(size_t)s3 * 64 + lane];
    acc0 += __shfl(ex0, k, 64) * bflo(v0.x);
    acc1 += __shfl(ex1, k, 64) * bfhi(v0.x);
    acc2 += __shfl(ex2, k, 64) * bflo(v0.y);
    acc3 += __shfl(ex3, k, 64) * bfhi(v0.y);
    acc0 += __shfl(ex0, k + 1, 64) * bflo(v1.x);
    acc1 += __shfl(ex1, k + 1, 64) * bfhi(v1.x);
    acc2 += __shfl(ex2, k + 1, 64) * bflo(v1.y);
    acc3 += __shfl(ex3, k + 1, 64) * bfhi(v1.y);
    acc0 += __shfl(ex0, k + 2, 64) * bflo(v2.x);
    acc1 += __shfl(ex1, k + 2, 64) * bfhi(v2.x);
    acc2 += __shfl(ex2, k + 2, 64) * bflo(v2.y);
    acc3 += __shfl(ex3, k + 2, 64) * bfhi(v2.y);
    acc0 += __shfl(ex0, k + 3, 64) * bflo(v3.x);
    acc1 += __shfl(ex1, k + 3, 64) * bfhi(v3.x);
    acc2 += __shfl(ex2, k + 3, 64) * bflo(v3.y);
    acc3 += __shfl(ex3, k + 3, 64) * bfhi(v3.y);
  }
  for (; k < deg; ++k) {
    int sk = __shfl(src, k, 64);
    uint2 v = h2[(size_t)sk * 64 + lane];
    acc0 += __shfl(ex0, k, 64) * bflo(v.x);
    acc1 += __shfl(ex1, k, 64) * bfhi(v.x);
    acc2 += __shfl(ex2, k, 64) * bflo(v.y);
    acc3 += __shfl(ex3, k, 64) * bfhi(v.y);
  }
  float outc = 0.25f * (acc0 * i0 + acc1 * i1 + acc2 * i2 + acc3 * i3) + bias[lane];
  int r = rows[e];
  atomicAdd(&agg[(size_t)r * 64 + lane], outc);
  if (lane == 0) atomicAdd(&degc[r], 1);
}

// ---------------- Pass 5: scatter-mean normalize + final linear ----------------
__global__ __launch_bounds__(256) void k_final(
    const float* __restrict__ agg, const int* __restrict__ degc,
    const float* __restrict__ wgt, const float* __restrict__ wb,
    float* __restrict__ out, int N) {
  __shared__ float wtt[64 * 65];     // wtt[k*65 + c] = wgt[c*64 + k]
  const int t = threadIdx.x;
#pragma unroll
  for (int i = 0; i < 16; ++i) {
    int idx = t + i * 256;                       // idx = c*64 + k
    wtt[(idx & 63) * 65 + (idx >> 6)] = wgt[idx];
  }
  __syncthreads();
  const int w = t >> 6, lane = t & 63;
  int n = blockIdx.x * 4 + w;
  if (n >= N) return;
  int dg = degc[n];
  float av = dg > 0 ? agg[(size_t)n * 64 + lane] / (float)dg : 0.f;
  float o = 0.f;
#pragma unroll
  for (int k = 0; k < 64; ++k) {
    o += __shfl(av, k, 64) * wtt[k * 65 + lane];
  }
  out[(size_t)n * 64 + lane] = o + wb[lane];
}

extern "C" void kernel_launch(void* const* d_in, const int* in_sizes, int n_in,
                              void* d_out, int out_size, void* d_ws, size_t ws_size,
                              hipStream_t stream) {
  const float* x       = (const float*)d_in[0];
  const int*   ei      = (const int*)d_in[1];
  const int*   rows    = (const int*)d_in[2];
  const float* W       = (const float*)d_in[3];
  const float* att_src = (const float*)d_in[4];
  const float* att_dst = (const float*)d_in[5];
  const float* bias    = (const float*)d_in[6];
  const float* wgt     = (const float*)d_in[7];
  const float* wb      = (const float*)d_in[8];

  const int E = in_sizes[0] / 64;     // 131072
  const int M = in_sizes[1] / 2;      // 2097152
  const int N = out_size / 64;        // 16384

  char* p = (char*)d_ws;
  unsigned short* h2 = (unsigned short*)p;  p += (size_t)E * 256 * 2;  // 64MB
  unsigned short* xb = (unsigned short*)p;  p += (size_t)E * 64 * 2;   // 16MB
  int*   csr   = (int*)p;                   p += (size_t)E * CAP * 4;  // 32MB
  float* a_src = (float*)p;                 p += (size_t)E * 4 * 4;    // 2MB
  float* a_dst = (float*)p;                 p += (size_t)E * 4 * 4;    // 2MB
  int*   cnt   = (int*)p;                   p += (size_t)E * 4;        // 512KB
  float* agg   = (float*)p;                 p += (size_t)N * 64 * 4;   // 4MB
  int*   degc  = (int*)p;                   p += (size_t)N * 4;        // 64KB
  unsigned short* Wb = (unsigned short*)p;  p += 16384 * 2;            // 32KB
  float* vs    = (float*)p;                 p += 512 * 4;              // 2KB

  hipMemsetAsync(cnt, 0, (size_t)E * 4, stream);
  hipMemsetAsync(agg, 0, (size_t)N * 64 * 4 + (size_t)N * 4, stream);  // agg + degc

  k_prevs<<<64, 256, 0, stream>>>(W, att_src, att_dst, Wb, vs);
  k_cast<<<E / 4, 256, 0, stream>>>(x, vs, xb, a_src, a_dst, E);
  k_proj<<<E / 64, 256, 0, stream>>>(xb, Wb, h2);

  int Mtot = M + E;
  k_fill<<<(Mtot + 255) / 256, 256, 0, stream>>>(ei, M, E, cnt, csr);

  k_agg<<<E / 4, 256, 0, stream>>>(
      (const uint2*)h2, (const float4*)a_src, (const float4*)a_dst, cnt, csr,
      rows, bias, agg, degc, E);

  k_final<<<(N + 3) / 4, 256, 0, stream>>>(agg, degc, wgt, wb, (float*)d_out, N);
}

// Round 3
// 318.197 us; speedup vs baseline: 2.3001x; 1.5634x over previous
//
#include <hip/hip_runtime.h>

// GAT on line graph. Pipeline (round 3):
//   k_prevs : cast W->bf16; vs[8][64] = W^T @ att_{src,dst}
//   k_fused : heterogeneous grid —
//             proj blocks: x fp32 -> bf16 frags in-register, MFMA h=x@W^T,
//                          exact fp32 a_src/a_dst via vs, h2 stored packed bf16
//             fill blocks: bucket 4 edges/thread by dst (cap 64) incl self loops
//   k_agg   : per-dst wave softmax (denominator-only) + gather; alpha/src
//             staged in LDS (broadcast reads), pre-normalized
//   k_final : scatter-mean normalize + 64x64 linear

#define CAP 64

using frag16 = __attribute__((ext_vector_type(8))) short;  // 8 bf16
using f32x4  = __attribute__((ext_vector_type(4))) float;

__device__ __forceinline__ float wave_reduce_sum(float v) {
#pragma unroll
  for (int off = 32; off > 0; off >>= 1) v += __shfl_xor(v, off, 64);
  return v;
}

// round-to-nearest (ties up) f32 -> bf16: <=0.5 ulp, 2 VALU ops
__device__ __forceinline__ unsigned short f2bf(float f) {
  union { float f; unsigned u; } v; v.f = f;
  return (unsigned short)((v.u + 0x8000u) >> 16);
}
__device__ __forceinline__ float bflo(unsigned u) {
  union { unsigned u; float f; } v; v.u = u << 16; return v.f;
}
__device__ __forceinline__ float bfhi(unsigned u) {
  union { unsigned u; float f; } v; v.u = u & 0xffff0000u; return v.f;
}

// ---------------- Pass 0: W cast + vs precompute ----------------
__global__ __launch_bounds__(256) void k_prevs(
    const float* __restrict__ W, const float* __restrict__ att_src,
    const float* __restrict__ att_dst, unsigned short* __restrict__ Wb,
    float* __restrict__ vs) {
  int t = blockIdx.x * 256 + threadIdx.x;    // 64 blocks -> 16384
  Wb[t] = f2bf(W[t]);
  if (blockIdx.x < 2) {
    int o = blockIdx.x * 256 + threadIdx.x;  // 0..511
    int j = o >> 6, c = o & 63;              // j: 0..3 src heads, 4..7 dst heads
    const float* att = (j < 4) ? att_src : att_dst;
    int hh = j & 3;
    float s = 0.f;
    for (int ch = 0; ch < 64; ++ch)
      s += W[(size_t)(hh * 64 + ch) * 64 + c] * att[hh * 64 + ch];
    vs[o] = s;
  }
}

// ---------------- Fused: projection blocks + fill blocks ----------------
__device__ __forceinline__ void proj_body(
    const float* __restrict__ x, const unsigned short* __restrict__ Wb,
    const float* __restrict__ vs, unsigned short* __restrict__ h2,
    float* __restrict__ a_src, float* __restrict__ a_dst, int bid,
    float* vsl /*LDS 512 floats*/) {
  const int t = threadIdx.x;
  if (t < 128) ((float4*)vsl)[t] = ((const float4*)vs)[t];
  __syncthreads();
  const int w = t >> 6, lane = t & 63, l15 = lane & 15, l4 = lane >> 4;
  const int e0 = bid * 64 + w * 16;
  const int row = e0 + l15;

  // Load this lane's 16 k-values of row `row`: k = l4*8..+7 and 32+l4*8..+7
  const float4* xp = (const float4*)(x + (size_t)row * 64);
  float4 v0 = xp[l4 * 2], v1 = xp[l4 * 2 + 1];
  float4 v2 = xp[8 + l4 * 2], v3 = xp[8 + l4 * 2 + 1];
  float xa[16] = {v0.x, v0.y, v0.z, v0.w, v1.x, v1.y, v1.z, v1.w,
                  v2.x, v2.y, v2.z, v2.w, v3.x, v3.y, v3.z, v3.w};

  // bf16 A-frags (same k-order as B-frags)
  frag16 a0, a1;
#pragma unroll
  for (int i = 0; i < 8; ++i) {
    a0[i] = (short)f2bf(xa[i]);
    a1[i] = (short)f2bf(xa[8 + i]);
  }

  // Exact fp32 attention dots: a_{src,dst}[row][h] = x[row] . vs[j]
  float pj[8];
#pragma unroll
  for (int j = 0; j < 8; ++j) {
    const float4* q = (const float4*)(vsl + j * 64 + l4 * 8);
    const float4* qb = (const float4*)(vsl + j * 64 + 32 + l4 * 8);
    float4 q0 = q[0], q1 = q[1], q2 = qb[0], q3 = qb[1];
    float s = xa[0] * q0.x + xa[1] * q0.y + xa[2] * q0.z + xa[3] * q0.w
            + xa[4] * q1.x + xa[5] * q1.y + xa[6] * q1.z + xa[7] * q1.w
            + xa[8] * q2.x + xa[9] * q2.y + xa[10] * q2.z + xa[11] * q2.w
            + xa[12] * q3.x + xa[13] * q3.y + xa[14] * q3.z + xa[15] * q3.w;
    s += __shfl_xor(s, 16, 64);
    s += __shfl_xor(s, 32, 64);
    pj[j] = s;
  }
  if (l4 == 0) {
    *(float4*)&a_src[(size_t)row * 4] = make_float4(pj[0], pj[1], pj[2], pj[3]);
    *(float4*)&a_dst[(size_t)row * 4] = make_float4(pj[4], pj[5], pj[6], pj[7]);
  }

  // MFMA: 16 col-tiles of 16 (heads*ch = 256 outputs)
  f32x4 acc[16];
#pragma unroll
  for (int nt = 0; nt < 16; ++nt) {
    const unsigned short* bp = Wb + (size_t)(nt * 16 + l15) * 64 + l4 * 8;
    frag16 b0 = *(const frag16*)(bp);
    frag16 b1 = *(const frag16*)(bp + 32);
    f32x4 c = {0.f, 0.f, 0.f, 0.f};
    c = __builtin_amdgcn_mfma_f32_16x16x32_bf16(a0, b0, c, 0, 0, 0);
    c = __builtin_amdgcn_mfma_f32_16x16x32_bf16(a1, b1, c, 0, 0, 0);
    acc[nt] = c;
  }

  // Direct packed-bf16 writeout: h2 row = 256 bf16, pos ch*4 + head.
  // C mapping (m89): row_local = l4*4 + r, col = nt*16 + l15;
  // col = head*64 + ch -> ch = (nt&3)*16 + l15, head = nt>>2.
#pragma unroll
  for (int nt0 = 0; nt0 < 4; ++nt0) {
    int ch = nt0 * 16 + l15;
#pragma unroll
    for (int r = 0; r < 4; ++r) {
      int rrow = e0 + l4 * 4 + r;
      ushort4 vv;
      vv.x = f2bf(acc[nt0][r]);
      vv.y = f2bf(acc[nt0 + 4][r]);
      vv.z = f2bf(acc[nt0 + 8][r]);
      vv.w = f2bf(acc[nt0 + 12][r]);
      *(ushort4*)&h2[(size_t)rrow * 256 + ch * 4] = vv;
    }
  }
}

__device__ __forceinline__ void fill_body(
    const int* __restrict__ ei, int M, int E,
    int* __restrict__ cnt, int* __restrict__ csr, int bid) {
  const int Mtot = M + E;
  const int base = bid * 1024 + threadIdx.x;
  int mm[4], ss[4], dd[4];
#pragma unroll
  for (int i = 0; i < 4; ++i) {
    int m = base + i * 256;
    mm[i] = m;
    if (m < Mtot) {
      if (m < M) { ss[i] = ei[m]; dd[i] = ei[M + m]; }
      else       { ss[i] = m - M; dd[i] = m - M; }   // self loop
    }
  }
  int pos[4];
#pragma unroll
  for (int i = 0; i < 4; ++i)
    if (mm[i] < Mtot) pos[i] = atomicAdd(&cnt[dd[i]], 1);
#pragma unroll
  for (int i = 0; i < 4; ++i)
    if (mm[i] < Mtot && pos[i] < CAP) csr[(size_t)dd[i] * CAP + pos[i]] = ss[i];
}

__global__ __launch_bounds__(256, 4) void k_fused(
    const float* __restrict__ x, const unsigned short* __restrict__ Wb,
    const float* __restrict__ vs, unsigned short* __restrict__ h2,
    float* __restrict__ a_src, float* __restrict__ a_dst,
    const int* __restrict__ ei, int M, int E,
    int* __restrict__ cnt, int* __restrict__ csr,
    int nproj, int nfill) {
  __shared__ float vsl[512];
  const int bid = blockIdx.x;
  // Interleave: even -> fill, odd -> proj (while both remain), then leftovers.
  int npair = 2 * min(nproj, nfill);
  if (bid < npair) {
    if (bid & 1) proj_body(x, Wb, vs, h2, a_src, a_dst, bid >> 1, vsl);
    else         fill_body(ei, M, E, cnt, csr, bid >> 1);
  } else {
    int r = bid - npair;
    if (nfill > nproj) fill_body(ei, M, E, cnt, csr, nproj + r);
    else               proj_body(x, Wb, vs, h2, a_src, a_dst, nfill + r, vsl);
  }
}

// ---------------- Aggregation: softmax + gather ----------------
__global__ __launch_bounds__(256) void k_agg(
    const uint2* __restrict__ h2, const float4* __restrict__ a_src,
    const float4* __restrict__ a_dst, const int* __restrict__ cnt,
    const int* __restrict__ csr, const int* __restrict__ rows,
    const float* __restrict__ bias, float* __restrict__ agg,
    int* __restrict__ degc, int E) {
  __shared__ float4 alds[4 * 64];
  __shared__ int    slds[4 * 64];
  const int w = threadIdx.x >> 6, lane = threadIdx.x & 63;
  const int e = blockIdx.x * 4 + w;          // E % 4 == 0, no guard needed

  int deg = cnt[e];
  if (deg > CAP) deg = CAP;
  float4 ad = a_dst[e];

  int src = 0;
  float ex0 = 0.f, ex1 = 0.f, ex2 = 0.f, ex3 = 0.f;
  if (lane < deg) {
    src = csr[(size_t)e * CAP + lane];
    float4 as = a_src[src];
    float l0 = as.x + ad.x; l0 = l0 > 0.f ? l0 : 0.2f * l0;
    float l1 = as.y + ad.y; l1 = l1 > 0.f ? l1 : 0.2f * l1;
    float l2 = as.z + ad.z; l2 = l2 > 0.f ? l2 : 0.2f * l2;
    float l3 = as.w + ad.w; l3 = l3 > 0.f ? l3 : 0.2f * l3;
    ex0 = __expf(l0); ex1 = __expf(l1); ex2 = __expf(l2); ex3 = __expf(l3);
  }
  float i0 = 1.f / (wave_reduce_sum(ex0) + 1e-16f);
  float i1 = 1.f / (wave_reduce_sum(ex1) + 1e-16f);
  float i2 = 1.f / (wave_reduce_sum(ex2) + 1e-16f);
  float i3 = 1.f / (wave_reduce_sum(ex3) + 1e-16f);

  // stage pre-normalized alphas + srcs in LDS (broadcast reads in the loop)
  alds[w * 64 + lane] = make_float4(ex0 * i0, ex1 * i1, ex2 * i2, ex3 * i3);
  slds[w * 64 + lane] = src;
  __syncthreads();

  float acc0 = 0.f, acc1 = 0.f, acc2 = 0.f, acc3 = 0.f;
  int k = 0;
  for (; k + 4 <= deg; k += 4) {
    int s0 = slds[w * 64 + k],     s1 = slds[w * 64 + k + 1];
    int s2 = slds[w * 64 + k + 2], s3 = slds[w * 64 + k + 3];
    uint2 v0 = h2[(size_t)s0 * 64 + lane];
    uint2 v1 = h2[(size_t)s1 * 64 + lane];
    uint2 v2 = h2[(size_t)s2 * 64 + lane];
    uint2 v3 = h2[(size_t)s3 * 64 + lane];
    float4 A0 = alds[w * 64 + k],     A1 = alds[w * 64 + k + 1];
    float4 A2 = alds[w * 64 + k + 2], A3 = alds[w * 64 + k + 3];
    acc0 = fmaf(A0.x, bflo(v0.x), acc0); acc1 = fmaf(A0.y, bfhi(v0.x), acc1);
    acc2 = fmaf(A0.z, bflo(v0.y), acc2); acc3 = fmaf(A0.w, bfhi(v0.y), acc3);
    acc0 = fmaf(A1.x, bflo(v1.x), acc0); acc1 = fmaf(A1.y, bfhi(v1.x), acc1);
    acc2 = fmaf(A1.z, bflo(v1.y), acc2); acc3 = fmaf(A1.w, bfhi(v1.y), acc3);
    acc0 = fmaf(A2.x, bflo(v2.x), acc0); acc1 = fmaf(A2.y, bfhi(v2.x), acc1);
    acc2 = fmaf(A2.z, bflo(v2.y), acc2); acc3 = fmaf(A2.w, bfhi(v2.y), acc3);
    acc0 = fmaf(A3.x, bflo(v3.x), acc0); acc1 = fmaf(A3.y, bfhi(v3.x), acc1);
    acc2 = fmaf(A3.z, bflo(v3.y), acc2); acc3 = fmaf(A3.w, bfhi(v3.y), acc3);
  }
  for (; k < deg; ++k) {
    int sk = slds[w * 64 + k];
    float4 A = alds[w * 64 + k];
    uint2 v = h2[(size_t)sk * 64 + lane];
    acc0 = fmaf(A.x, bflo(v.x), acc0); acc1 = fmaf(A.y, bfhi(v.x), acc1);
    acc2 = fmaf(A.z, bflo(v.y), acc2); acc3 = fmaf(A.w, bfhi(v.y), acc3);
  }
  float outc = 0.25f * (acc0 + acc1 + acc2 + acc3) + bias[lane];
  int r = rows[e];
  atomicAdd(&agg[(size_t)r * 64 + lane], outc);
  if (lane == 0) atomicAdd(&degc[r], 1);
}

// ---------------- scatter-mean normalize + final linear ----------------
__global__ __launch_bounds__(256) void k_final(
    const float* __restrict__ agg, const int* __restrict__ degc,
    const float* __restrict__ wgt, const float* __restrict__ wb,
    float* __restrict__ out, int N) {
  __shared__ float wtt[64 * 65];
  const int t = threadIdx.x;
#pragma unroll
  for (int i = 0; i < 16; ++i) {
    int idx = t + i * 256;                       // idx = c*64 + k
    wtt[(idx & 63) * 65 + (idx >> 6)] = wgt[idx];
  }
  __syncthreads();
  const int w = t >> 6, lane = t & 63;
  int n = blockIdx.x * 4 + w;
  if (n >= N) return;
  int dg = degc[n];
  float av = dg > 0 ? agg[(size_t)n * 64 + lane] / (float)dg : 0.f;
  float o = 0.f;
#pragma unroll
  for (int k = 0; k < 64; ++k) {
    o += __shfl(av, k, 64) * wtt[k * 65 + lane];
  }
  out[(size_t)n * 64 + lane] = o + wb[lane];
}

extern "C" void kernel_launch(void* const* d_in, const int* in_sizes, int n_in,
                              void* d_out, int out_size, void* d_ws, size_t ws_size,
                              hipStream_t stream) {
  const float* x       = (const float*)d_in[0];
  const int*   ei      = (const int*)d_in[1];
  const int*   rows    = (const int*)d_in[2];
  const float* W       = (const float*)d_in[3];
  const float* att_src = (const float*)d_in[4];
  const float* att_dst = (const float*)d_in[5];
  const float* bias    = (const float*)d_in[6];
  const float* wgt     = (const float*)d_in[7];
  const float* wb      = (const float*)d_in[8];

  const int E = in_sizes[0] / 64;     // 131072
  const int M = in_sizes[1] / 2;      // 2097152
  const int N = out_size / 64;        // 16384

  char* p = (char*)d_ws;
  unsigned short* h2 = (unsigned short*)p;  p += (size_t)E * 256 * 2;  // 64MB
  int*   csr   = (int*)p;                   p += (size_t)E * CAP * 4;  // 32MB
  float* a_src = (float*)p;                 p += (size_t)E * 4 * 4;    // 2MB
  float* a_dst = (float*)p;                 p += (size_t)E * 4 * 4;    // 2MB
  int*   cnt   = (int*)p;                   p += (size_t)E * 4;        // 512KB
  float* agg   = (float*)p;                 p += (size_t)N * 64 * 4;   // 4MB
  int*   degc  = (int*)p;                   p += (size_t)N * 4;        // 64KB
  unsigned short* Wb = (unsigned short*)p;  p += 16384 * 2;            // 32KB
  float* vs    = (float*)p;                 p += 512 * 4;              // 2KB

  hipMemsetAsync(cnt, 0, (size_t)E * 4, stream);
  hipMemsetAsync(agg, 0, (size_t)N * 64 * 4 + (size_t)N * 4, stream);  // agg+degc

  k_prevs<<<64, 256, 0, stream>>>(W, att_src, att_dst, Wb, vs);

  const int Mtot = M + E;
  const int nproj = E / 64;                  // 2048
  const int nfill = (Mtot + 1023) / 1024;    // 2176
  k_fused<<<nproj + nfill, 256, 0, stream>>>(
      x, Wb, vs, h2, a_src, a_dst, ei, M, E, cnt, csr, nproj, nfill);

  k_agg<<<E / 4, 256, 0, stream>>>(
      (const uint2*)h2, (const float4*)a_src, (const float4*)a_dst, cnt, csr,
      rows, bias, agg, degc, E);

  k_final<<<(N + 3) / 4, 256, 0, stream>>>(agg, degc, wgt, wb, (float*)d_out, N);
}